// Round 3
// baseline (85.349 us; speedup 1.0000x reference)
//
#include <hip/hip_runtime.h>
#include <hip/hip_cooperative_groups.h>

namespace cg = cooperative_groups;

// out[b,n,m] = qx[b,n] + qy[b,m] + sum_e (w[e]/2)*|px+pyc| + ob
//   relu(u) = (u+|u|)/2 splits into rank-1 part (qx,qy) + abs part.
// Single cooperative kernel, 3 phases with grid.sync() between:
//   1) coeff = tanh(weights @ A_w^T + A_b)       (1024 wave-jobs)
//   2) px/pyc GEMMs + qx/qy epilogue             (256 blocks: (b,src,rowtile))
//   3) out tile contraction                       (256 blocks: (b,n-tile,m-tile))

#define B_ 8
#define NM 256
#define D_ 128
#define DIN 1024

// LDS map (51584 B static, aliased across phases):
//  phase2: S[16][132] @0 (8448), Wl[128][66] @8448 (33792), REDP[3*16*128] @8448 alias
//  phase3: PXs[64][132] @0, PYs[32][132] @33792, WHs @50688, QXl @51200, QYl @51456,
//          REDM[48*128] @0 alias PXs

__global__ __launch_bounds__(512, 2) void k_fused(
    const float* __restrict__ X, const float* __restrict__ Y,
    const float* __restrict__ wts, const float* __restrict__ Aw,
    const float* __restrict__ Ab, const float* __restrict__ lin_w,
    const float* __restrict__ lin_b, const float* __restrict__ out_w,
    const float* __restrict__ out_b, float* __restrict__ out,
    float* __restrict__ coeff, float* __restrict__ px,
    float* __restrict__ pyc, float* __restrict__ qx, float* __restrict__ qy)
{
    __shared__ __align__(16) char smem[51584];
    cg::grid_group grid = cg::this_grid();
    const int t = threadIdx.x;
    const int bx = blockIdx.x;

    // ---------------- phase 1: coeff ----------------
    {
        const int wv = t >> 6, lane = t & 63;
        const int gw = bx * 8 + wv;                 // 2048 waves, 1024 jobs
        if (gw < 1024) {
            const int b = gw >> 7, e = gw & 127;
            const float4* wr = (const float4*)(wts + b * DIN);
            const float4* ar = (const float4*)(Aw + (size_t)e * DIN);
            float s = 0.f;
#pragma unroll
            for (int i = 0; i < 4; ++i) {
                float4 wv4 = wr[i * 64 + lane];
                float4 av  = ar[i * 64 + lane];
                s += wv4.x * av.x + wv4.y * av.y + wv4.z * av.z + wv4.w * av.w;
            }
#pragma unroll
            for (int d = 32; d; d >>= 1) s += __shfl_xor(s, d, 64);
            if (lane == 0) coeff[b * 128 + e] = tanhf(s + Ab[e]);
        }
    }
    grid.sync();

    // ---------------- phase 2: px/pyc + qx/qy ----------------
    {
        float* S    = (float*)smem;            // [16][132]
        float* Wl   = (float*)(smem + 8448);   // [128][66], float2 granularity
        float* REDP = (float*)(smem + 8448);   // alias (used after Wl reads done)
        const int bsrc = bx >> 4, b = bsrc >> 1, src = bsrc & 1;
        const int r0 = (bx & 15) * 16;

        const float* Sg = (src ? Y : X) + (size_t)(b * NM + r0) * D_;
        {
            float4 v = ((const float4*)Sg)[t];
            if (!src) {
                float4 c = ((const float4*)(coeff + b * 128))[t & 31];
                v.x *= c.x; v.y *= c.y; v.z *= c.z; v.w *= c.w;
            }
            *(float4*)(&S[(t >> 5) * 132 + (t & 31) * 4]) = v;
        }

        const int tt = t & 127, kq = t >> 7;   // kq: reduction quarter
        const int er = tt & 31, rr = tt >> 5;
        float acc[4][4] = {};

        for (int pass = 0; pass < 2; ++pass) {
            if (pass) __syncthreads();         // drain pass-0 Wl reads
            for (int ii = t; ii < 2048; ii += 512) {
                int e = ii >> 4, k4 = ii & 15;
                float4 g = *(const float4*)(lin_w + (size_t)e * 256 + src * 128 +
                                            pass * 64 + k4 * 4);
                float* wp = &Wl[e * 66 + k4 * 4];
                *(float2*)wp       = make_float2(g.x, g.y);
                *(float2*)(wp + 2) = make_float2(g.z, g.w);
            }
            __syncthreads();
#pragma unroll
            for (int kt = 0; kt < 16; kt += 4) {
                const int kg = pass * 64 + kq * 16 + kt;
                float4 a[4]; float2 w0[4], w1[4];
#pragma unroll
                for (int i = 0; i < 4; ++i)
                    a[i] = *(const float4*)(&S[(rr + 4 * i) * 132 + kg]);
#pragma unroll
                for (int j = 0; j < 4; ++j) {
                    const float* wp = &Wl[(er + 32 * j) * 66 + kq * 16 + kt];
                    w0[j] = *(const float2*)wp;
                    w1[j] = *(const float2*)(wp + 2);
                }
#pragma unroll
                for (int i = 0; i < 4; ++i)
#pragma unroll
                    for (int j = 0; j < 4; ++j)
                        acc[i][j] += a[i].x * w0[j].x + a[i].y * w0[j].y +
                                     a[i].z * w1[j].x + a[i].w * w1[j].y;
            }
        }
        __syncthreads();                       // drain pass-1 reads before alias
        if (kq) {
            float* R = REDP + (size_t)(kq - 1) * 2048;
#pragma unroll
            for (int i = 0; i < 4; ++i)
#pragma unroll
                for (int j = 0; j < 4; ++j) R[(i * 4 + j) * 128 + tt] = acc[i][j];
        }
        __syncthreads();
        if (kq == 0) {
#pragma unroll
            for (int q = 0; q < 3; ++q)
#pragma unroll
                for (int i = 0; i < 4; ++i)
#pragma unroll
                    for (int j = 0; j < 4; ++j)
                        acc[i][j] += REDP[(size_t)q * 2048 + (i * 4 + j) * 128 + tt];
            float* Pg = (src ? pyc : px) + (size_t)(b * NM + r0) * D_;
            float qpart[4] = {0.f, 0.f, 0.f, 0.f};
#pragma unroll
            for (int i = 0; i < 4; ++i)
#pragma unroll
                for (int j = 0; j < 4; ++j) {
                    int e = er + 32 * j;
                    float v = acc[i][j];
                    if (src) v += lin_b[e];
                    Pg[(rr + 4 * i) * D_ + e] = v;
                    qpart[i] = fmaf(0.5f * out_w[e], v, qpart[i]);
                }
            float* Qg = (src ? qy : qx) + b * NM + r0;
#pragma unroll
            for (int i = 0; i < 4; ++i) {
                float s = qpart[i];
#pragma unroll
                for (int d2 = 16; d2; d2 >>= 1) s += __shfl_xor(s, d2, 64);
                if (er == 0) Qg[rr + 4 * i] = s;
            }
        }
    }
    grid.sync();

    // ---------------- phase 3: out ----------------
    {
        float* PXs  = (float*)smem;             // [64][132]
        float* PYs  = (float*)(smem + 33792);   // [32][132]
        float* WHs  = (float*)(smem + 50688);   // [128]
        float* QXl  = (float*)(smem + 51200);   // [64]
        float* QYl  = (float*)(smem + 51456);   // [32]
        float* REDM = (float*)smem;             // alias PXs after compute

        const int b = bx >> 5, n0 = ((bx >> 3) & 3) * 64, m0 = (bx & 7) * 32;

        const float4* pxg = (const float4*)(px + (size_t)(b * NM + n0) * D_);
        for (int i = t; i < 2048; i += 512)
            *(float4*)(&PXs[(i >> 5) * 132 + (i & 31) * 4]) = pxg[i];
        const float4* pyg = (const float4*)(pyc + (size_t)(b * NM + m0) * D_);
        for (int i = t; i < 1024; i += 512)
            *(float4*)(&PYs[(i >> 5) * 132 + (i & 31) * 4]) = pyg[i];
        if (t < 128) WHs[t] = 0.5f * out_w[t];
        else if (t < 192) QXl[t - 128] = qx[b * NM + n0 + (t - 128)];
        else if (t < 224) QYl[t - 192] = qy[b * NM + m0 + (t - 192)];
        __syncthreads();

        const int w = t >> 6, eq = w & 3, half = w >> 2;
        const int s = half * 64 + (t & 63);
        const int nr = s >> 3, mr = s & 7;
        const int e0 = eq * 32;

        float4 wr[8];
#pragma unroll
        for (int q = 0; q < 8; ++q) wr[q] = *(const float4*)(&WHs[e0 + 4 * q]);

        float acc[4][4] = {};
#pragma unroll
        for (int es = 0; es < 32; es += 4) {
            float4 xa[4], ya[4];
            float4 wv = wr[es >> 2];
#pragma unroll
            for (int i = 0; i < 4; ++i)
                xa[i] = *(const float4*)(&PXs[(nr + 16 * i) * 132 + e0 + es]);
#pragma unroll
            for (int j = 0; j < 4; ++j)
                ya[j] = *(const float4*)(&PYs[(mr + 8 * j) * 132 + e0 + es]);
#pragma unroll
            for (int i = 0; i < 4; ++i)
#pragma unroll
                for (int j = 0; j < 4; ++j) {
                    float t0 = xa[i].x + ya[j].x;
                    float t1 = xa[i].y + ya[j].y;
                    float t2 = xa[i].z + ya[j].z;
                    float t3 = xa[i].w + ya[j].w;
                    acc[i][j] = fmaf(fabsf(t0), wv.x, acc[i][j]);
                    acc[i][j] = fmaf(fabsf(t1), wv.y, acc[i][j]);
                    acc[i][j] = fmaf(fabsf(t2), wv.z, acc[i][j]);
                    acc[i][j] = fmaf(fabsf(t3), wv.w, acc[i][j]);
                }
        }
        __syncthreads();                        // drain PXs/PYs reads before alias
        if (eq) {
#pragma unroll
            for (int i = 0; i < 4; ++i)
#pragma unroll
                for (int j = 0; j < 4; ++j)
                    REDM[((eq - 1) * 16 + i * 4 + j) * 128 + s] = acc[i][j];
        }
        __syncthreads();
        if (eq == 0) {
            const float ob = out_b[0];
            float* og = out + (size_t)b * NM * NM;
#pragma unroll
            for (int i = 0; i < 4; ++i) {
                float qn = QXl[nr + 16 * i];
#pragma unroll
                for (int j = 0; j < 4; ++j) {
                    float v = acc[i][j];
#pragma unroll
                    for (int p = 0; p < 3; ++p)
                        v += REDM[(p * 16 + i * 4 + j) * 128 + s];
                    og[(n0 + nr + 16 * i) * NM + m0 + mr + 8 * j] =
                        v + qn + QYl[mr + 8 * j] + ob;
                }
            }
        }
    }
}

extern "C" void kernel_launch(void* const* d_in, const int* in_sizes, int n_in,
                              void* d_out, int out_size, void* d_ws, size_t ws_size,
                              hipStream_t stream) {
    const float* X      = (const float*)d_in[0];
    const float* Y      = (const float*)d_in[1];
    const float* wts    = (const float*)d_in[2];
    const float* A_w    = (const float*)d_in[3];
    const float* A_b    = (const float*)d_in[4];
    const float* lin_w  = (const float*)d_in[5];
    const float* lin_b  = (const float*)d_in[6];
    const float* out_w  = (const float*)d_in[7];
    const float* out_b  = (const float*)d_in[8];
    float* out = (float*)d_out;

    float* ws    = (float*)d_ws;
    float* coeff = ws;                    // 1024
    float* px    = coeff + 1024;          // 8*256*128
    float* pyc   = px + B_ * NM * D_;     // 8*256*128
    float* qx    = pyc + B_ * NM * D_;    // 2048
    float* qy    = qx + B_ * NM;          // 2048

    void* args[] = {&X, &Y, &wts, &A_w, &A_b, &lin_w, &lin_b, &out_w, &out_b,
                    &out, &coeff, &px, &pyc, &qx, &qy};
    hipLaunchCooperativeKernel((const void*)k_fused, dim3(256), dim3(512),
                               args, 0, stream);
}

// Round 4
// 33.312 us; speedup vs baseline: 2.5621x; 2.5621x over previous
//
#include <hip/hip_runtime.h>

// out[b,n,m] = qx[b,n] + qy[b,m] + sum_e (w[e]/2)*|px+pyc| + ob
//   relu(u) = (u+|u|)/2 splits into rank-1 part (qx,qy) + abs part.
// 2 kernels: k_proj (coeff inline + both projections + qx/qy), k_main.

#define B_ 8
#define NM 256
#define D_ 128
#define DIN 1024

// ---- K1: coeff (inline for src=0 blocks) + px/pyc + qx/qy ----
// grid 256: bsrc = bx>>4 (b = bsrc>>1, src = bsrc&1), rowtile = bx&15.
// block 512 = 8 waves: kq = t>>7 (k-quarter), tt = t&127 (er = tt&31, rr = tt>>5).
// Two k-passes of 64 staged in Wl; each thread accumulates 16 outputs x 32 k.
__global__ __launch_bounds__(512) void k_proj(
    const float* __restrict__ X, const float* __restrict__ Y,
    const float* __restrict__ wts, const float* __restrict__ Aw,
    const float* __restrict__ Ab, const float* __restrict__ lin_w,
    const float* __restrict__ lin_b, const float* __restrict__ out_w,
    float* __restrict__ px, float* __restrict__ pyc,
    float* __restrict__ qx, float* __restrict__ qy)
{
    __shared__ __align__(16) char smem[67328];
    float* S    = (float*)smem;               // [16][132]           8448 B
    float* Wl   = (float*)(smem + 8448);      // [128][66]          33792 B
    float* RED  = (float*)(smem + 42240);     // 3*2048 f           24576 B
    float* wtsS = (float*)(smem + 42240);     // alias RED (prologue only)
    float* cofS = (float*)(smem + 66816);     // [128]

    const int bx = blockIdx.x;
    const int bsrc = bx >> 4, b = bsrc >> 1, src = bsrc & 1;
    const int r0 = (bx & 15) * 16;
    const int t = threadIdx.x;

    // stage S raw (+ wts for src=0)
    const float* Sg = (src ? Y : X) + (size_t)(b * NM + r0) * D_;
    {
        float4 v = ((const float4*)Sg)[t];
        *(float4*)(&S[(t >> 5) * 132 + (t & 31) * 4]) = v;
        if (!src && t < 256) ((float4*)wtsS)[t] = ((const float4*)(wts + b * DIN))[t];
    }
    __syncthreads();

    if (!src) {
        // coeff[e] = tanh(sum_k wts[b,k]*Aw[e,k] + Ab[e]); e = t>>2, h = t&3.
        const int e = t >> 2, h = t & 3;
        const float4* ar = (const float4*)(Aw + (size_t)e * DIN + h * 256);
        const float4* wr = (const float4*)(wtsS + h * 256);
        float s = 0.f;
#pragma unroll 4
        for (int k = 0; k < 64; ++k) {
            float4 a = ar[k], w = wr[k];
            s += a.x * w.x + a.y * w.y + a.z * w.z + a.w * w.w;
        }
        s += __shfl_xor(s, 1, 64);
        s += __shfl_xor(s, 2, 64);
        if (h == 0) cofS[e] = tanhf(s + Ab[e]);
        __syncthreads();
        // scale S rows by coeff
        {
            float4* sp = (float4*)(&S[(t >> 5) * 132 + (t & 31) * 4]);
            float4 v = *sp;
            float4 c = ((const float4*)cofS)[t & 31];
            v.x *= c.x; v.y *= c.y; v.z *= c.z; v.w *= c.w;
            *sp = v;
        }
    }

    const int kq = t >> 7, tt = t & 127;
    const int er = tt & 31, rr = tt >> 5;
    float acc[4][4] = {};

    for (int p = 0; p < 2; ++p) {
        __syncthreads();
        // stage Wl: lin_w[e][src*128 + p*64 + k], float2-granular, stride 66
        for (int ii = t; ii < 2048; ii += 512) {
            int e = ii >> 4, k4 = ii & 15;
            float4 g = *(const float4*)(lin_w + (size_t)e * 256 + src * 128 +
                                        p * 64 + k4 * 4);
            float* wp = &Wl[e * 66 + k4 * 4];
            *(float2*)(wp)     = make_float2(g.x, g.y);
            *(float2*)(wp + 2) = make_float2(g.z, g.w);
        }
        __syncthreads();
#pragma unroll
        for (int kt = 0; kt < 16; kt += 4) {
            const int kl = kq * 16 + kt;       // local k in pass
            const int kg = p * 64 + kl;        // global k (for S)
            float4 a[4]; float2 w0[4], w1[4];
#pragma unroll
            for (int i = 0; i < 4; ++i)
                a[i] = *(const float4*)(&S[(rr + 4 * i) * 132 + kg]);
#pragma unroll
            for (int j = 0; j < 4; ++j) {
                const float* wp = &Wl[(er + 32 * j) * 66 + kl];
                w0[j] = *(const float2*)(wp);
                w1[j] = *(const float2*)(wp + 2);
            }
#pragma unroll
            for (int i = 0; i < 4; ++i)
#pragma unroll
                for (int j = 0; j < 4; ++j)
                    acc[i][j] += a[i].x * w0[j].x + a[i].y * w0[j].y +
                                 a[i].z * w1[j].x + a[i].w * w1[j].y;
        }
    }
    __syncthreads();

    if (kq) {
        float* R = RED + (size_t)(kq - 1) * 2048;
#pragma unroll
        for (int i = 0; i < 4; ++i)
#pragma unroll
            for (int j = 0; j < 4; ++j) R[(i * 4 + j) * 128 + tt] = acc[i][j];
    }
    __syncthreads();
    if (kq == 0) {
#pragma unroll
        for (int q = 0; q < 3; ++q)
#pragma unroll
            for (int i = 0; i < 4; ++i)
#pragma unroll
                for (int j = 0; j < 4; ++j)
                    acc[i][j] += RED[(size_t)q * 2048 + (i * 4 + j) * 128 + tt];
        float* Pg = (src ? pyc : px) + (size_t)(b * NM + r0) * D_;
        float qpart[4] = {0.f, 0.f, 0.f, 0.f};
#pragma unroll
        for (int i = 0; i < 4; ++i)
#pragma unroll
            for (int j = 0; j < 4; ++j) {
                int e = er + 32 * j;
                float v = acc[i][j];
                if (src) v += lin_b[e];
                Pg[(rr + 4 * i) * D_ + e] = v;
                qpart[i] = fmaf(0.5f * out_w[e], v, qpart[i]);
            }
        float* Qg = (src ? qy : qx) + b * NM + r0;
#pragma unroll
        for (int i = 0; i < 4; ++i) {
            float s = qpart[i];
#pragma unroll
            for (int d2 = 16; d2; d2 >>= 1) s += __shfl_xor(s, d2, 64);
            if (er == 0) Qg[rr + 4 * i] = s;
        }
    }
}

// ---- K2: main |.| contraction, e-split-4. grid 256 flat, block 512. ----
// b = bx&7 (XCD affinity), tile = bx>>3: n0 = (tile>>3)*64, m0 = (tile&7)*32.
__global__ __launch_bounds__(512) void k_main(
    const float* __restrict__ px, const float* __restrict__ pyc,
    const float* __restrict__ qx, const float* __restrict__ qy,
    const float* __restrict__ out_w, const float* __restrict__ out_b,
    float* __restrict__ out) {
    __shared__ float PXs[64 * 132];
    __shared__ float PYs[32 * 132];
    __shared__ float RED[48 * 128];
    __shared__ float WHs[128];
    __shared__ float QXl[64], QYl[32];

    const int bx = blockIdx.x;
    const int b = bx & 7, tile = bx >> 3;
    const int n0 = (tile >> 3) * 64, m0 = (tile & 7) * 32;
    const int t = threadIdx.x;

    const float4* pxg = (const float4*)(px + (size_t)(b * NM + n0) * D_);
    for (int i = t; i < 2048; i += 512)
        *(float4*)(&PXs[(i >> 5) * 132 + (i & 31) * 4]) = pxg[i];
    const float4* pyg = (const float4*)(pyc + (size_t)(b * NM + m0) * D_);
    for (int i = t; i < 1024; i += 512)
        *(float4*)(&PYs[(i >> 5) * 132 + (i & 31) * 4]) = pyg[i];
    if (t < 128) WHs[t] = 0.5f * out_w[t];
    else if (t < 192) QXl[t - 128] = qx[b * NM + n0 + (t - 128)];
    else if (t < 224) QYl[t - 192] = qy[b * NM + m0 + (t - 192)];
    __syncthreads();

    const int w = t >> 6, eq = w & 3, half = w >> 2;
    const int s = half * 64 + (t & 63);
    const int nr = s >> 3, mr = s & 7;
    const int e0 = eq * 32;

    float4 wr[8];
#pragma unroll
    for (int q = 0; q < 8; ++q) wr[q] = *(const float4*)(&WHs[e0 + 4 * q]);

    float acc[4][4] = {};
#pragma unroll
    for (int es = 0; es < 32; es += 4) {
        float4 xa[4], ya[4];
        float4 wv = wr[es >> 2];
#pragma unroll
        for (int i = 0; i < 4; ++i)
            xa[i] = *(const float4*)(&PXs[(nr + 16 * i) * 132 + e0 + es]);
#pragma unroll
        for (int j = 0; j < 4; ++j)
            ya[j] = *(const float4*)(&PYs[(mr + 8 * j) * 132 + e0 + es]);
#pragma unroll
        for (int i = 0; i < 4; ++i)
#pragma unroll
            for (int j = 0; j < 4; ++j) {
                float t0 = xa[i].x + ya[j].x;
                float t1 = xa[i].y + ya[j].y;
                float t2 = xa[i].z + ya[j].z;
                float t3 = xa[i].w + ya[j].w;
                acc[i][j] = fmaf(fabsf(t0), wv.x, acc[i][j]);
                acc[i][j] = fmaf(fabsf(t1), wv.y, acc[i][j]);
                acc[i][j] = fmaf(fabsf(t2), wv.z, acc[i][j]);
                acc[i][j] = fmaf(fabsf(t3), wv.w, acc[i][j]);
            }
    }

    if (eq) {
#pragma unroll
        for (int i = 0; i < 4; ++i)
#pragma unroll
            for (int j = 0; j < 4; ++j)
                RED[((eq - 1) * 16 + i * 4 + j) * 128 + s] = acc[i][j];
    }
    __syncthreads();
    if (eq == 0) {
        const float ob = out_b[0];
        float* og = out + (size_t)b * NM * NM;
#pragma unroll
        for (int i = 0; i < 4; ++i) {
            float qn = QXl[nr + 16 * i];
#pragma unroll
            for (int j = 0; j < 4; ++j) {
                float v = acc[i][j];
#pragma unroll
                for (int p = 0; p < 3; ++p)
                    v += RED[(p * 16 + i * 4 + j) * 128 + s];
                og[(n0 + nr + 16 * i) * NM + m0 + mr + 8 * j] =
                    v + qn + QYl[mr + 8 * j] + ob;
            }
        }
    }
}

extern "C" void kernel_launch(void* const* d_in, const int* in_sizes, int n_in,
                              void* d_out, int out_size, void* d_ws, size_t ws_size,
                              hipStream_t stream) {
    const float* X      = (const float*)d_in[0];
    const float* Y      = (const float*)d_in[1];
    const float* wts    = (const float*)d_in[2];
    const float* A_w    = (const float*)d_in[3];
    const float* A_b    = (const float*)d_in[4];
    const float* lin_w  = (const float*)d_in[5];
    const float* lin_b  = (const float*)d_in[6];
    const float* out_w  = (const float*)d_in[7];
    const float* out_b  = (const float*)d_in[8];
    float* out = (float*)d_out;

    float* ws  = (float*)d_ws;
    float* px  = ws;                   // 8*256*128
    float* pyc = px + B_ * NM * D_;    // 8*256*128
    float* qx  = pyc + B_ * NM * D_;   // 2048
    float* qy  = qx + B_ * NM;         // 2048

    k_proj<<<dim3(256), 512, 0, stream>>>(X, Y, wts, A_w, A_b, lin_w, lin_b,
                                          out_w, px, pyc, qx, qy);
    k_main<<<dim3(256), 512, 0, stream>>>(px, pyc, qx, qy, out_w, out_b, out);
}

// Round 5
// 24.391 us; speedup vs baseline: 3.4992x; 1.3657x over previous
//
#include <hip/hip_runtime.h>

// out[b,n,m] = qx[b,n] + qy[b,m] + sum_e (w[e]/2)*|px+pyc| + ob
//   relu(u) = (u+|u|)/2 splits into rank-1 part (qx,qy) + abs part.
// 3 kernels: k_coeff, k_proj (f32 GEMM, f16 stores), k_main (f16 pk/dot2).

#define B_ 8
#define NM 256
#define D_ 128
#define DIN 1024

typedef _Float16 hh;
typedef _Float16 hh2 __attribute__((ext_vector_type(2)));
struct __attribute__((aligned(16))) H8 { hh2 h[4]; };

__device__ __forceinline__ float dot2acc(hh2 a, hh2 b, float c) {
#if __has_builtin(__builtin_amdgcn_fdot2)
    return __builtin_amdgcn_fdot2(a, b, c, false);
#else
    return c + (float)a.x * (float)b.x + (float)a.y * (float)b.y;
#endif
}

// ---- K1: coeff[b][e] = tanh(W[b,:].Aw[e,:] + Ab[e]), one wave per (b,e) ----
__global__ void k_coeff(const float* __restrict__ W, const float* __restrict__ Aw,
                        const float* __restrict__ Ab, float* __restrict__ coeff) {
    int wid  = (blockIdx.x * blockDim.x + threadIdx.x) >> 6;  // 0..1023
    int lane = threadIdx.x & 63;
    int b = wid >> 7, e = wid & 127;
    const float4* wr = (const float4*)(W + b * DIN);
    const float4* ar = (const float4*)(Aw + (size_t)e * DIN);
    float s = 0.f;
#pragma unroll
    for (int i = 0; i < 4; ++i) {
        float4 wv = wr[i * 64 + lane];
        float4 av = ar[i * 64 + lane];
        s += wv.x * av.x + wv.y * av.y + wv.z * av.z + wv.w * av.w;
    }
#pragma unroll
    for (int d = 32; d; d >>= 1) s += __shfl_xor(s, d, 64);
    if (lane == 0) coeff[b * 128 + e] = tanhf(s + Ab[e]);
}

// ---- K2: px/pyc (f16 out) + qx/qy. grid 256 flat, block 512, k-split-4 ----
// bsrc = bx>>4 (b = bsrc>>1, src = bsrc&1), rowtile = bx&15.
__global__ __launch_bounds__(512) void k_proj(
    const float* __restrict__ X, const float* __restrict__ Y,
    const float* __restrict__ coeff, const float* __restrict__ lin_w,
    const float* __restrict__ lin_b, const float* __restrict__ out_w,
    hh* __restrict__ px, hh* __restrict__ pyc,
    float* __restrict__ qx, float* __restrict__ qy)
{
    __shared__ __align__(16) char smem[66816];
    float* S   = (float*)smem;               // [16][132]   8448 B
    float* Wl  = (float*)(smem + 8448);      // [128][66]  33792 B
    float* RED = (float*)(smem + 42240);     // 3*2048 f   24576 B

    const int bx = blockIdx.x;
    const int bsrc = bx >> 4, b = bsrc >> 1, src = bsrc & 1;
    const int r0 = (bx & 15) * 16;
    const int t = threadIdx.x;

    // stage S (coeff-folded for X): 512 float4, one per thread
    const float* Sg = (src ? Y : X) + (size_t)(b * NM + r0) * D_;
    {
        float4 v = ((const float4*)Sg)[t];
        if (!src) {
            float4 c = ((const float4*)(coeff + b * 128))[t & 31];
            v.x *= c.x; v.y *= c.y; v.z *= c.z; v.w *= c.w;
        }
        *(float4*)(&S[(t >> 5) * 132 + (t & 31) * 4]) = v;
    }

    const int kq = t >> 7, tt = t & 127;
    const int er = tt & 31, rr = tt >> 5;
    float acc[4][4] = {};

    for (int p = 0; p < 2; ++p) {
        __syncthreads();
        for (int ii = t; ii < 2048; ii += 512) {
            int e = ii >> 4, k4 = ii & 15;
            float4 g = *(const float4*)(lin_w + (size_t)e * 256 + src * 128 +
                                        p * 64 + k4 * 4);
            float* wp = &Wl[e * 66 + k4 * 4];
            *(float2*)(wp)     = make_float2(g.x, g.y);
            *(float2*)(wp + 2) = make_float2(g.z, g.w);
        }
        __syncthreads();
#pragma unroll
        for (int kt = 0; kt < 16; kt += 4) {
            const int kl = kq * 16 + kt;
            const int kg = p * 64 + kl;
            float4 a[4]; float2 w0[4], w1[4];
#pragma unroll
            for (int i = 0; i < 4; ++i)
                a[i] = *(const float4*)(&S[(rr + 4 * i) * 132 + kg]);
#pragma unroll
            for (int j = 0; j < 4; ++j) {
                const float* wp = &Wl[(er + 32 * j) * 66 + kl];
                w0[j] = *(const float2*)(wp);
                w1[j] = *(const float2*)(wp + 2);
            }
#pragma unroll
            for (int i = 0; i < 4; ++i)
#pragma unroll
                for (int j = 0; j < 4; ++j)
                    acc[i][j] += a[i].x * w0[j].x + a[i].y * w0[j].y +
                                 a[i].z * w1[j].x + a[i].w * w1[j].y;
        }
    }

    __syncthreads();
    if (kq) {
        float* R = RED + (size_t)(kq - 1) * 2048;
#pragma unroll
        for (int i = 0; i < 4; ++i)
#pragma unroll
            for (int j = 0; j < 4; ++j) R[(i * 4 + j) * 128 + tt] = acc[i][j];
    }
    __syncthreads();
    if (kq == 0) {
#pragma unroll
        for (int q = 0; q < 3; ++q)
#pragma unroll
            for (int i = 0; i < 4; ++i)
#pragma unroll
                for (int j = 0; j < 4; ++j)
                    acc[i][j] += RED[(size_t)q * 2048 + (i * 4 + j) * 128 + tt];
        hh* Pg = (src ? pyc : px) + (size_t)(b * NM + r0) * D_;
        float qpart[4] = {0.f, 0.f, 0.f, 0.f};
#pragma unroll
        for (int i = 0; i < 4; ++i)
#pragma unroll
            for (int j = 0; j < 4; ++j) {
                int e = er + 32 * j;
                float v = acc[i][j];
                if (src) v += lin_b[e];
                Pg[(rr + 4 * i) * D_ + e] = (hh)v;
                qpart[i] = fmaf(0.5f * out_w[e], v, qpart[i]);
            }
        float* Qg = (src ? qy : qx) + b * NM + r0;
#pragma unroll
        for (int i = 0; i < 4; ++i) {
            float s = qpart[i];
#pragma unroll
            for (int d2 = 16; d2; d2 >>= 1) s += __shfl_xor(s, d2, 64);
            if (er == 0) Qg[rr + 4 * i] = s;
        }
    }
}

// ---- K3: main |.| contraction, f16 packed, e-split-4. grid 256, block 512 ----
__global__ __launch_bounds__(512) void k_main(
    const hh* __restrict__ px, const hh* __restrict__ pyc,
    const float* __restrict__ qx, const float* __restrict__ qy,
    const float* __restrict__ out_w, const float* __restrict__ out_b,
    float* __restrict__ out) {
    __shared__ hh PXs[64 * 136];      // 17408 B, stride 272 B (16B-aligned rows)
    __shared__ hh PYs[32 * 136];      //  8704 B
    __shared__ float RED[48 * 128];   // 24576 B
    __shared__ hh WHs[128];
    __shared__ float QXl[64], QYl[32];

    const int bx = blockIdx.x;
    const int b = bx & 7, tile = bx >> 3;
    const int n0 = (tile >> 3) * 64, m0 = (tile & 7) * 32;
    const int t = threadIdx.x;

    const uint4* pxg = (const uint4*)(px + (size_t)(b * NM + n0) * D_);
    for (int i = t; i < 1024; i += 512)
        *(uint4*)(&PXs[(i >> 4) * 136 + (i & 15) * 8]) = pxg[i];
    const uint4* pyg = (const uint4*)(pyc + (size_t)(b * NM + m0) * D_);
    if (t < 512)
        *(uint4*)(&PYs[(t >> 4) * 136 + (t & 15) * 8]) = pyg[t];
    if (t < 128) WHs[t] = (hh)(0.5f * out_w[t]);
    else if (t < 192) QXl[t - 128] = qx[b * NM + n0 + (t - 128)];
    else if (t < 224) QYl[t - 192] = qy[b * NM + m0 + (t - 192)];
    __syncthreads();

    const int w = t >> 6, eq = w & 3, half = w >> 2;
    const int s = half * 64 + (t & 63);
    const int nr = s >> 3, mr = s & 7;
    const int e0 = eq * 32;

    hh2 wv[16];
#pragma unroll
    for (int q = 0; q < 16; ++q) wv[q] = *(const hh2*)(&WHs[e0 + 2 * q]);

    float acc[4][4] = {};
#pragma unroll
    for (int es = 0; es < 4; ++es) {          // 8 e per step
        H8 xa[4], ya[4];
#pragma unroll
        for (int i = 0; i < 4; ++i)
            xa[i] = *(const H8*)(&PXs[(nr + 16 * i) * 136 + e0 + es * 8]);
#pragma unroll
        for (int j = 0; j < 4; ++j)
            ya[j] = *(const H8*)(&PYs[(mr + 8 * j) * 136 + e0 + es * 8]);
#pragma unroll
        for (int i = 0; i < 4; ++i)
#pragma unroll
            for (int j = 0; j < 4; ++j)
#pragma unroll
                for (int p = 0; p < 4; ++p) {
                    hh2 u = xa[i].h[p] + ya[j].h[p];
                    unsigned uu;
                    __builtin_memcpy(&uu, &u, 4);
                    uu &= 0x7fff7fffu;
                    hh2 au;
                    __builtin_memcpy(&au, &uu, 4);
                    acc[i][j] = dot2acc(au, wv[es * 4 + p], acc[i][j]);
                }
    }

    if (eq) {
#pragma unroll
        for (int i = 0; i < 4; ++i)
#pragma unroll
            for (int j = 0; j < 4; ++j)
                RED[((eq - 1) * 16 + i * 4 + j) * 128 + s] = acc[i][j];
    }
    __syncthreads();
    if (eq == 0) {
        const float ob = out_b[0];
        float* og = out + (size_t)b * NM * NM;
#pragma unroll
        for (int i = 0; i < 4; ++i) {
            float qn = QXl[nr + 16 * i];
#pragma unroll
            for (int j = 0; j < 4; ++j) {
                float v = acc[i][j];
#pragma unroll
                for (int p = 0; p < 3; ++p)
                    v += RED[(p * 16 + i * 4 + j) * 128 + s];
                og[(n0 + nr + 16 * i) * NM + m0 + mr + 8 * j] =
                    v + qn + QYl[mr + 8 * j] + ob;
            }
        }
    }
}

extern "C" void kernel_launch(void* const* d_in, const int* in_sizes, int n_in,
                              void* d_out, int out_size, void* d_ws, size_t ws_size,
                              hipStream_t stream) {
    const float* X      = (const float*)d_in[0];
    const float* Y      = (const float*)d_in[1];
    const float* wts    = (const float*)d_in[2];
    const float* A_w    = (const float*)d_in[3];
    const float* A_b    = (const float*)d_in[4];
    const float* lin_w  = (const float*)d_in[5];
    const float* lin_b  = (const float*)d_in[6];
    const float* out_w  = (const float*)d_in[7];
    const float* out_b  = (const float*)d_in[8];
    float* out = (float*)d_out;

    hh*    px    = (hh*)d_ws;                       // 8*256*128 halves
    hh*    pyc   = px + B_ * NM * D_;               // 8*256*128 halves
    float* qx    = (float*)(pyc + B_ * NM * D_);    // 2048 f
    float* qy    = qx + 2048;                       // 2048 f
    float* coeff = qy + 2048;                       // 1024 f

    k_coeff<<<256, 256, 0, stream>>>(wts, A_w, A_b, coeff);
    k_proj<<<dim3(256), 512, 0, stream>>>(X, Y, coeff, lin_w, lin_b, out_w,
                                          px, pyc, qx, qy);
    k_main<<<dim3(256), 512, 0, stream>>>(px, pyc, qx, qy, out_w, out_b, out);
}